// Round 21
// baseline (680.532 us; speedup 1.0000x reference)
//
#include <hip/hip_runtime.h>
#include <stdint.h>

#define TSTEPS 1024
#define S 8          // timesteps per super-iter (layer skew)
#define NK 130       // 1024/S + 2 pipeline-drain super-iters
#define L2E 1.4426950408889634f
#define XPITCH 1028

typedef float v2f __attribute__((ext_vector_type(2)));
typedef float v4f __attribute__((ext_vector_type(4)));

__device__ __forceinline__ float rcpf_(float v) { return __builtin_amdgcn_rcpf(v); }
__device__ __forceinline__ float ex2(float v) { return __builtin_amdgcn_exp2f(v); }
#define PKFMA(a, b, c) __builtin_elementwise_fma((a), (b), (c))

// ONLY HW-proven symmetric quad_perm controls: 0xB1 (xor1), 0x4E (xor2).
template <int CTRL>
__device__ __forceinline__ float dppf(float v) {
    return __int_as_float(__builtin_amdgcn_update_dpp(
        0, __float_as_int(v), CTRL, 0xF, 0xF, true));
}
template <int CTRL>
__device__ __forceinline__ v2f dpp2(v2f v) {
    return (v2f){dppf<CTRL>(v.x), dppf<CTRL>(v.y)};
}

// Opaque loads: value is asm-produced -> cannot be rematerialized as a load.
__device__ __forceinline__ v2f ldg2(const float* p) {
    v2f r; uint64_t a = (uint64_t)p;
    asm volatile("global_load_dwordx2 %0, %1, off\n\ts_waitcnt vmcnt(0)"
                 : "=v"(r) : "v"(a));
    return r;
}
__device__ __forceinline__ float ldg1(const float* p) {
    float r; uint64_t a = (uint64_t)p;
    asm volatile("global_load_dword %0, %1, off\n\ts_waitcnt vmcnt(0)"
                 : "=v"(r) : "v"(a));
    return r;
}

// Replicate a 16-float LDS h vector using ONE b128 + 12 DPP movs.
// Lane block k = u&3 reads h[4k..4k+3]; butterfly (xor1, xor2) gathers
// blocks in order [B(k), B(k^1), B(k^2), B(k^3)] -> dst[2m..2m+1] = slot m.
// Weights must be loaded with matching col-block permutation 4*(k^m).
#define RDX(dst, p, k4)                                                    \
    do {                                                                   \
        v4f t = *(const v4f*)((p) + (k4));                                 \
        dst[0] = __builtin_shufflevector(t, t, 0, 1);                      \
        dst[1] = __builtin_shufflevector(t, t, 2, 3);                      \
        dst[2] = dpp2<0xB1>(dst[0]);                                       \
        dst[3] = dpp2<0xB1>(dst[1]);                                       \
        dst[4] = dpp2<0x4E>(dst[0]);                                       \
        dst[5] = dpp2<0x4E>(dst[1]);                                       \
        dst[6] = dpp2<0x4E>(dst[2]);                                       \
        dst[7] = dpp2<0x4E>(dst[3]);                                       \
    } while (0)

#define DOT8(w, h, seed)                                                   \
    ({                                                                     \
        v2f _a = PKFMA(w[0], h[0], (seed));                                \
        _a = PKFMA(w[1], h[1], _a); _a = PKFMA(w[2], h[2], _a);            \
        _a = PKFMA(w[3], h[3], _a); _a = PKFMA(w[4], h[4], _a);            \
        _a = PKFMA(w[5], h[5], _a); _a = PKFMA(w[6], h[6], _a);            \
        _a = PKFMA(w[7], h[7], _a);                                        \
        _a.x + _a.y;                                                       \
    })
#define DOT16(wa, ha, wb, hb, seed)                                        \
    ({                                                                     \
        v2f _a = PKFMA(wa[0], ha[0], (seed));                              \
        _a = PKFMA(wa[1], ha[1], _a); _a = PKFMA(wa[2], ha[2], _a);        \
        _a = PKFMA(wa[3], ha[3], _a); _a = PKFMA(wa[4], ha[4], _a);        \
        _a = PKFMA(wa[5], ha[5], _a); _a = PKFMA(wa[6], ha[6], _a);        \
        _a = PKFMA(wa[7], ha[7], _a);                                      \
        _a = PKFMA(wb[0], hb[0], _a); _a = PKFMA(wb[1], hb[1], _a);        \
        _a = PKFMA(wb[2], hb[2], _a); _a = PKFMA(wb[3], hb[3], _a);        \
        _a = PKFMA(wb[4], hb[4], _a); _a = PKFMA(wb[5], hb[5], _a);        \
        _a = PKFMA(wb[6], hb[6], _a); _a = PKFMA(wb[7], hb[7], _a);        \
        _a.x + _a.y;                                                       \
    })

// R20 structure (3 role waves x 4 seqs, S-step skew, double-buffered rings,
// one barrier per super-iter) with LDS-pipe traffic cut ~2.3x: every h
// replication is 1 b128 + 12 DPP movs instead of 4 b128 (the LDS pipe is
// per-CU shared by all 12 waves and was the measured wall at ~1000 cy/step).
__global__ __launch_bounds__(192, 3)
__attribute__((amdgpu_waves_per_eu(3, 3)))
void gru3_dx(
    const float* __restrict__ x,      // [4096,1024,1]
    const float* __restrict__ w_ih0,  // [48,1]
    const float* __restrict__ w_ih12, // [2,48,16]
    const float* __restrict__ w_hh,   // [3,48,16]
    const float* __restrict__ b_ih,   // [3,48]
    const float* __restrict__ b_hh,   // [3,48]
    const float* __restrict__ fc_w,   // [5,16]
    const float* __restrict__ fc_b,   // [5]
    float* __restrict__ out)          // [4096,5]
{
    __shared__ float xs[4][XPITCH];          // padded x rows
    __shared__ float hring[3][2][S][4][16];  // [layer][buf][slot][seq][unit]
    __shared__ float h2f[4][16];             // head staging

    const int tid = threadIdx.x;
    const int role = tid >> 6;         // wave = layer
    const int lane = tid & 63;
    const int s = lane >> 4;           // seq within block (0..3)
    const int u = lane & 15;           // hidden unit
    const int kx = u & 3;              // h block owned after 1-b128 read
    const int k4 = kx * 4;             // float offset of own block
    const int seq = blockIdx.x * 4 + s;

    // ---- stage x (coalesced float4, padded rows) + zero rings
    {
        const float4* xg = (const float4*)(x + (size_t)blockIdx.x * 4 * TSTEPS);
#pragma unroll
        for (int j = 0; j < 6; ++j) {
            int idx = tid + 192 * j;
            if (idx < 1024) {
                float4 v = xg[idx];
                *(float4*)&xs[idx >> 8][(idx & 255) * 4] = v;
            }
        }
#pragma unroll
        for (int j = 0; j < 16; ++j)
            ((float*)hring)[tid + 192 * j] = 0.f;
    }
    __syncthreads();

    // weight col base for block slot m: 4*(kx^m) + 2*p  (matches RDX order)
#define WCOL(m, p) (4 * (kx ^ (m)) + 2 * (p))

    if (role == 0) {
        // ---- layer 0: t = K*S + j
        v2f wr[8], wz[8], wn[8];
#pragma unroll
        for (int m = 0; m < 4; ++m)
#pragma unroll
            for (int p = 0; p < 2; ++p) {
                wr[2 * m + p] = ldg2(w_hh + (u) * 16 + WCOL(m, p)) * -L2E;
                wz[2 * m + p] = ldg2(w_hh + (16 + u) * 16 + WCOL(m, p)) * -L2E;
                wn[2 * m + p] = ldg2(w_hh + (32 + u) * 16 + WCOL(m, p)) * (2.f * L2E);
            }
        const float wxr = ldg1(w_ih0 + u) * -L2E;
        const float wxz = ldg1(w_ih0 + 16 + u) * -L2E;
        const float wxn = ldg1(w_ih0 + 32 + u) * (2.f * L2E);
        const v2f sbr = {-(ldg1(b_ih + u) + ldg1(b_hh + u)) * L2E, 0.f};
        const v2f sbz = {-(ldg1(b_ih + 16 + u) + ldg1(b_hh + 16 + u)) * L2E, 0.f};
        const v2f sbn = {ldg1(b_hh + 32 + u) * (2.f * L2E), 0.f};
        const float bnx = ldg1(b_ih + 32 + u) * (2.f * L2E);
        float* cur = &hring[0][0][0][s][0];
        float* prv = &hring[0][1][0][s][0];
        float hown = 0.f;
        for (int K = 0; K < NK; ++K) {
            if (K < 128) {
                v4f xq0 = *(const v4f*)&xs[s][K * S];
                v4f xq1 = *(const v4f*)&xs[s][K * S + 4];
#pragma unroll
                for (int j = 0; j < S; ++j) {
                    const float* rb = (j == 0) ? (prv + (S - 1) * 64)
                                               : (cur + (j - 1) * 64);
                    v2f hp[8];
                    RDX(hp, rb, k4);
                    float xt = (j < 4) ? xq0[j] : xq1[j - 4];
                    float sr = fmaf(wxr, xt, DOT8(wr, hp, sbr));
                    float sz = fmaf(wxz, xt, DOT8(wz, hp, sbz));
                    float snh = DOT8(wn, hp, sbn);
                    float r = rcpf_(1.f + ex2(sr));
                    float z = rcpf_(1.f + ex2(sz));
                    float ut = fmaf(r, snh, fmaf(wxn, xt, bnx));
                    float n = fmaf(-2.f, rcpf_(ex2(ut) + 1.f), 1.f);
                    hown = fmaf(z, hown - n, n);
                    cur[j * 64 + u] = hown;
                }
            }
            __syncthreads();
            float* t_ = cur; cur = prv; prv = t_;
        }
    } else if (role == 1) {
        // ---- layer 1: t = (K-1)*S + j
        v2f wr[8], wz[8], wn[8], vr[8], vz[8], vn[8];
#pragma unroll
        for (int m = 0; m < 4; ++m)
#pragma unroll
            for (int p = 0; p < 2; ++p) {
                wr[2 * m + p] = ldg2(w_hh + (48 + u) * 16 + WCOL(m, p)) * -L2E;
                wz[2 * m + p] = ldg2(w_hh + (48 + 16 + u) * 16 + WCOL(m, p)) * -L2E;
                wn[2 * m + p] = ldg2(w_hh + (48 + 32 + u) * 16 + WCOL(m, p)) * (2.f * L2E);
                vr[2 * m + p] = ldg2(w_ih12 + (u) * 16 + WCOL(m, p)) * -L2E;
                vz[2 * m + p] = ldg2(w_ih12 + (16 + u) * 16 + WCOL(m, p)) * -L2E;
                vn[2 * m + p] = ldg2(w_ih12 + (32 + u) * 16 + WCOL(m, p)) * (2.f * L2E);
            }
        const v2f sbr = {-(ldg1(b_ih + 48 + u) + ldg1(b_hh + 48 + u)) * L2E, 0.f};
        const v2f sbz = {-(ldg1(b_ih + 64 + u) + ldg1(b_hh + 64 + u)) * L2E, 0.f};
        const v2f sbn = {ldg1(b_hh + 80 + u) * (2.f * L2E), 0.f};
        const v2f sbx = {ldg1(b_ih + 80 + u) * (2.f * L2E), 0.f};
        float* in0 = &hring[0][0][0][s][0];
        float* in1 = &hring[0][1][0][s][0];
        float* my0 = &hring[1][0][0][s][0];
        float* my1 = &hring[1][1][0][s][0];
        float* inp = in1;
        float* mycur = my0; float* myprv = my1;
        float hown = 0.f;
        for (int K = 0; K < NK; ++K) {
            if (K >= 1 && K < 129) {
#pragma unroll
                for (int j = 0; j < S; ++j) {
                    const float* rin = inp + j * 64;
                    const float* rown = (j == 0) ? (myprv + (S - 1) * 64)
                                                 : (mycur + (j - 1) * 64);
                    v2f hin[8], hp[8];
                    RDX(hin, rin, k4);
                    RDX(hp, rown, k4);
                    float sr = DOT16(wr, hp, vr, hin, sbr);
                    float sz = DOT16(wz, hp, vz, hin, sbz);
                    float snh = DOT8(wn, hp, sbn);
                    float snx = DOT8(vn, hin, sbx);
                    float r = rcpf_(1.f + ex2(sr));
                    float z = rcpf_(1.f + ex2(sz));
                    float ut = fmaf(r, snh, snx);
                    float n = fmaf(-2.f, rcpf_(ex2(ut) + 1.f), 1.f);
                    hown = fmaf(z, hown - n, n);
                    mycur[j * 64 + u] = hown;
                }
            }
            __syncthreads();
            float* t_ = inp == in0 ? in1 : in0; inp = t_;
            t_ = mycur; mycur = myprv; myprv = t_;
        }
    } else {
        // ---- layer 2: t = (K-2)*S + j
        v2f wr[8], wz[8], wn[8], vr[8], vz[8], vn[8];
#pragma unroll
        for (int m = 0; m < 4; ++m)
#pragma unroll
            for (int p = 0; p < 2; ++p) {
                wr[2 * m + p] = ldg2(w_hh + (96 + u) * 16 + WCOL(m, p)) * -L2E;
                wz[2 * m + p] = ldg2(w_hh + (96 + 16 + u) * 16 + WCOL(m, p)) * -L2E;
                wn[2 * m + p] = ldg2(w_hh + (96 + 32 + u) * 16 + WCOL(m, p)) * (2.f * L2E);
                vr[2 * m + p] = ldg2(w_ih12 + (48 + u) * 16 + WCOL(m, p)) * -L2E;
                vz[2 * m + p] = ldg2(w_ih12 + (48 + 16 + u) * 16 + WCOL(m, p)) * -L2E;
                vn[2 * m + p] = ldg2(w_ih12 + (48 + 32 + u) * 16 + WCOL(m, p)) * (2.f * L2E);
            }
        const v2f sbr = {-(ldg1(b_ih + 96 + u) + ldg1(b_hh + 96 + u)) * L2E, 0.f};
        const v2f sbz = {-(ldg1(b_ih + 112 + u) + ldg1(b_hh + 112 + u)) * L2E, 0.f};
        const v2f sbn = {ldg1(b_hh + 128 + u) * (2.f * L2E), 0.f};
        const v2f sbx = {ldg1(b_ih + 128 + u) * (2.f * L2E), 0.f};
        float* in0 = &hring[1][0][0][s][0];
        float* in1 = &hring[1][1][0][s][0];
        float* my0 = &hring[2][0][0][s][0];
        float* my1 = &hring[2][1][0][s][0];
        float* inp = in1;
        float* mycur = my0; float* myprv = my1;
        float hown = 0.f;
        for (int K = 0; K < NK; ++K) {
            if (K >= 2) {
#pragma unroll
                for (int j = 0; j < S; ++j) {
                    const float* rin = inp + j * 64;
                    const float* rown = (j == 0) ? (myprv + (S - 1) * 64)
                                                 : (mycur + (j - 1) * 64);
                    v2f hin[8], hp[8];
                    RDX(hin, rin, k4);
                    RDX(hp, rown, k4);
                    float sr = DOT16(wr, hp, vr, hin, sbr);
                    float sz = DOT16(wz, hp, vz, hin, sbz);
                    float snh = DOT8(wn, hp, sbn);
                    float snx = DOT8(vn, hin, sbx);
                    float r = rcpf_(1.f + ex2(sr));
                    float z = rcpf_(1.f + ex2(sz));
                    float ut = fmaf(r, snh, snx);
                    float n = fmaf(-2.f, rcpf_(ex2(ut) + 1.f), 1.f);
                    hown = fmaf(z, hown - n, n);
                    mycur[j * 64 + u] = hown;
                }
            }
            __syncthreads();
            float* t_ = inp == in0 ? in1 : in0; inp = t_;
            t_ = mycur; mycur = myprv; myprv = t_;
        }
        // ---- head on h2(1023)
        h2f[s][u] = hown;
        if (u < 5) {
            float acc = fc_b[u];
#pragma unroll
            for (int j = 0; j < 16; ++j)
                acc = fmaf(fc_w[u * 16 + j], h2f[s][j], acc);
            out[seq * 5 + u] = acc;
        }
    }
#undef WCOL
}

extern "C" void kernel_launch(void* const* d_in, const int* in_sizes, int n_in,
                              void* d_out, int out_size, void* d_ws, size_t ws_size,
                              hipStream_t stream) {
    const float* x      = (const float*)d_in[0];
    const float* w_ih0  = (const float*)d_in[1];
    const float* w_ih12 = (const float*)d_in[2];
    const float* w_hh   = (const float*)d_in[3];
    const float* b_ih   = (const float*)d_in[4];
    const float* b_hh   = (const float*)d_in[5];
    const float* fc_w   = (const float*)d_in[6];
    const float* fc_b   = (const float*)d_in[7];
    float* out = (float*)d_out;

    // 1024 blocks x 192 threads (3 waves: L0,L1,L2; 4 seqs/block)
    gru3_dx<<<1024, 192, 0, stream>>>(
        x, w_ih0, w_ih12, w_hh, b_ih, b_hh, fc_w, fc_b, out);
}

// Round 22
// 519.447 us; speedup vs baseline: 1.3101x; 1.3101x over previous
//
#include <hip/hip_runtime.h>
#include <stdint.h>

#define TSTEPS 1024
#define S 8          // timesteps per super-iter (layer skew)
#define NK 130       // 1024/S + 2 pipeline-drain super-iters
#define L2E 1.4426950408889634f
#define XPITCH 1028  // padded x row (dwords)

typedef float v2f __attribute__((ext_vector_type(2)));
typedef float v4f __attribute__((ext_vector_type(4)));

__device__ __forceinline__ float rcpf_(float v) { return __builtin_amdgcn_rcpf(v); }
__device__ __forceinline__ float ex2(float v) { return __builtin_amdgcn_exp2f(v); }
#define PKFMA(a, b, c) __builtin_elementwise_fma((a), (b), (c))

// Opaque loads: value is asm-produced -> cannot be rematerialized as a load.
__device__ __forceinline__ v2f ldg2(const float* p) {
    v2f r; uint64_t a = (uint64_t)p;
    asm volatile("global_load_dwordx2 %0, %1, off\n\ts_waitcnt vmcnt(0)"
                 : "=v"(r) : "v"(a));
    return r;
}
__device__ __forceinline__ float ldg1(const float* p) {
    float r; uint64_t a = (uint64_t)p;
    asm volatile("global_load_dword %0, %1, off\n\ts_waitcnt vmcnt(0)"
                 : "=v"(r) : "v"(a));
    return r;
}

// read 16 consecutive LDS floats (one h vector) into 8 v2f (4x ds_read_b128,
// independently issued -> latencies overlap)
#define RDH(dst, p)                                                        \
    do {                                                                   \
        v4f a0 = *(const v4f*)(p);                                         \
        v4f a1 = *(const v4f*)((p) + 4);                                   \
        v4f a2 = *(const v4f*)((p) + 8);                                   \
        v4f a3 = *(const v4f*)((p) + 12);                                  \
        dst[0] = __builtin_shufflevector(a0, a0, 0, 1);                    \
        dst[1] = __builtin_shufflevector(a0, a0, 2, 3);                    \
        dst[2] = __builtin_shufflevector(a1, a1, 0, 1);                    \
        dst[3] = __builtin_shufflevector(a1, a1, 2, 3);                    \
        dst[4] = __builtin_shufflevector(a2, a2, 0, 1);                    \
        dst[5] = __builtin_shufflevector(a2, a2, 2, 3);                    \
        dst[6] = __builtin_shufflevector(a3, a3, 0, 1);                    \
        dst[7] = __builtin_shufflevector(a3, a3, 2, 3);                    \
    } while (0)

// Two-accumulator dot chains: dependency depth 8->4 FMAs (DOT8) and
// 16->8 FMAs (DOT16), +1 v2f add each. Shortens the serial recurrence chain.
#define DOT8(w, h, seed)                                                   \
    ({                                                                     \
        v2f _a = PKFMA(w[0], h[0], (seed));                                \
        v2f _b = w[1] * h[1];                                              \
        _a = PKFMA(w[2], h[2], _a); _b = PKFMA(w[3], h[3], _b);            \
        _a = PKFMA(w[4], h[4], _a); _b = PKFMA(w[5], h[5], _b);            \
        _a = PKFMA(w[6], h[6], _a); _b = PKFMA(w[7], h[7], _b);            \
        _a = _a + _b;                                                      \
        _a.x + _a.y;                                                       \
    })
#define DOT16(wa, ha, wb, hb, seed)                                        \
    ({                                                                     \
        v2f _a = PKFMA(wa[0], ha[0], (seed));                              \
        v2f _b = wa[1] * ha[1];                                            \
        _a = PKFMA(wa[2], ha[2], _a); _b = PKFMA(wa[3], ha[3], _b);        \
        _a = PKFMA(wa[4], ha[4], _a); _b = PKFMA(wa[5], ha[5], _b);        \
        _a = PKFMA(wa[6], ha[6], _a); _b = PKFMA(wa[7], ha[7], _b);        \
        _a = PKFMA(wb[0], hb[0], _a); _b = PKFMA(wb[1], hb[1], _b);        \
        _a = PKFMA(wb[2], hb[2], _a); _b = PKFMA(wb[3], hb[3], _b);        \
        _a = PKFMA(wb[4], hb[4], _a); _b = PKFMA(wb[5], hb[5], _b);        \
        _a = PKFMA(wb[6], hb[6], _a); _b = PKFMA(wb[7], hb[7], _b);        \
        _a = _a + _b;                                                      \
        _a.x + _a.y;                                                       \
    })

// Block = 3 waves (one per layer) x 4 seqs. Layers skewed by S timesteps;
// cross-layer h handoff through double-buffered rings (buf = K&1), barrier
// once per super-iter. Own-layer recurrent reads are same-wave DS
// (program-ordered) and never wait on the barrier. [R20 structure, best 487us]
__global__ __launch_bounds__(192, 3)
__attribute__((amdgpu_waves_per_eu(3, 3)))
void gru3_sk8b(
    const float* __restrict__ x,      // [4096,1024,1]
    const float* __restrict__ w_ih0,  // [48,1]
    const float* __restrict__ w_ih12, // [2,48,16]
    const float* __restrict__ w_hh,   // [3,48,16]
    const float* __restrict__ b_ih,   // [3,48]
    const float* __restrict__ b_hh,   // [3,48]
    const float* __restrict__ fc_w,   // [5,16]
    const float* __restrict__ fc_b,   // [5]
    float* __restrict__ out)          // [4096,5]
{
    __shared__ float xs[4][XPITCH];          // padded x rows
    __shared__ float hring[3][2][S][4][16];  // [layer][buf][slot][seq][unit]
    __shared__ float h2f[4][16];             // head staging

    const int tid = threadIdx.x;
    const int role = tid >> 6;         // wave = layer
    const int lane = tid & 63;
    const int s = lane >> 4;           // seq within block (0..3)
    const int u = lane & 15;           // hidden unit
    const int seq = blockIdx.x * 4 + s;

    // ---- stage x (coalesced float4, padded rows) + zero rings
    {
        const float4* xg = (const float4*)(x + (size_t)blockIdx.x * 4 * TSTEPS);
#pragma unroll
        for (int j = 0; j < 6; ++j) {
            int idx = tid + 192 * j;
            if (idx < 1024) {
                float4 v = xg[idx];
                *(float4*)&xs[idx >> 8][(idx & 255) * 4] = v;
            }
        }
#pragma unroll
        for (int j = 0; j < 16; ++j)
            ((float*)hring)[tid + 192 * j] = 0.f;
    }
    __syncthreads();

    if (role == 0) {
        // ---- layer 0: t = K*S + j
        v2f wr[8], wz[8], wn[8];
#pragma unroll
        for (int m = 0; m < 8; ++m) {
            wr[m] = ldg2(w_hh + (u) * 16 + 2 * m) * -L2E;
            wz[m] = ldg2(w_hh + (16 + u) * 16 + 2 * m) * -L2E;
            wn[m] = ldg2(w_hh + (32 + u) * 16 + 2 * m) * (2.f * L2E);
        }
        const float wxr = ldg1(w_ih0 + u) * -L2E;
        const float wxz = ldg1(w_ih0 + 16 + u) * -L2E;
        const float wxn = ldg1(w_ih0 + 32 + u) * (2.f * L2E);
        const v2f sbr = {-(ldg1(b_ih + u) + ldg1(b_hh + u)) * L2E, 0.f};
        const v2f sbz = {-(ldg1(b_ih + 16 + u) + ldg1(b_hh + 16 + u)) * L2E, 0.f};
        const v2f sbn = {ldg1(b_hh + 32 + u) * (2.f * L2E), 0.f};
        const float bnx = ldg1(b_ih + 32 + u) * (2.f * L2E);
        float* cur = &hring[0][0][0][s][0];  // buf K&1 (slot stride 64 floats)
        float* prv = &hring[0][1][0][s][0];
        float hown = 0.f;
        for (int K = 0; K < NK; ++K) {
            if (K < 128) {
                v4f xq0 = *(const v4f*)&xs[s][K * S];
                v4f xq1 = *(const v4f*)&xs[s][K * S + 4];
#pragma unroll
                for (int j = 0; j < S; ++j) {
                    const float* rb = (j == 0) ? (prv + (S - 1) * 64)
                                               : (cur + (j - 1) * 64);
                    v2f hp[8];
                    RDH(hp, rb);
                    float xt = (j < 4) ? xq0[j] : xq1[j - 4];
                    float sr = fmaf(wxr, xt, DOT8(wr, hp, sbr));
                    float sz = fmaf(wxz, xt, DOT8(wz, hp, sbz));
                    float snh = DOT8(wn, hp, sbn);
                    float r = rcpf_(1.f + ex2(sr));
                    float z = rcpf_(1.f + ex2(sz));
                    float ut = fmaf(r, snh, fmaf(wxn, xt, bnx));
                    float n = fmaf(-2.f, rcpf_(ex2(ut) + 1.f), 1.f);
                    hown = fmaf(z, hown - n, n);
                    cur[j * 64 + u] = hown;
                }
            }
            __syncthreads();
            float* t_ = cur; cur = prv; prv = t_;
        }
    } else if (role == 1) {
        // ---- layer 1: t = (K-1)*S + j; input h0 from hring[0][(K-1)&1]
        v2f wr[8], wz[8], wn[8], vr[8], vz[8], vn[8];
#pragma unroll
        for (int m = 0; m < 8; ++m) {
            wr[m] = ldg2(w_hh + (48 + u) * 16 + 2 * m) * -L2E;
            wz[m] = ldg2(w_hh + (48 + 16 + u) * 16 + 2 * m) * -L2E;
            wn[m] = ldg2(w_hh + (48 + 32 + u) * 16 + 2 * m) * (2.f * L2E);
            vr[m] = ldg2(w_ih12 + (u) * 16 + 2 * m) * -L2E;
            vz[m] = ldg2(w_ih12 + (16 + u) * 16 + 2 * m) * -L2E;
            vn[m] = ldg2(w_ih12 + (32 + u) * 16 + 2 * m) * (2.f * L2E);
        }
        const v2f sbr = {-(ldg1(b_ih + 48 + u) + ldg1(b_hh + 48 + u)) * L2E, 0.f};
        const v2f sbz = {-(ldg1(b_ih + 64 + u) + ldg1(b_hh + 64 + u)) * L2E, 0.f};
        const v2f sbn = {ldg1(b_hh + 80 + u) * (2.f * L2E), 0.f};
        const v2f sbx = {ldg1(b_ih + 80 + u) * (2.f * L2E), 0.f};
        float* in0 = &hring[0][0][0][s][0];
        float* in1 = &hring[0][1][0][s][0];
        float* my0 = &hring[1][0][0][s][0];
        float* my1 = &hring[1][1][0][s][0];
        float* inp = in1;  // at K: in[(K-1)&1]
        float* mycur = my0; float* myprv = my1;
        float hown = 0.f;
        for (int K = 0; K < NK; ++K) {
            if (K >= 1 && K < 129) {
#pragma unroll
                for (int j = 0; j < S; ++j) {
                    const float* rin = inp + j * 64;
                    const float* rown = (j == 0) ? (myprv + (S - 1) * 64)
                                                 : (mycur + (j - 1) * 64);
                    v2f hin[8], hp[8];
                    RDH(hin, rin);
                    RDH(hp, rown);
                    float sr = DOT16(wr, hp, vr, hin, sbr);
                    float sz = DOT16(wz, hp, vz, hin, sbz);
                    float snh = DOT8(wn, hp, sbn);
                    float snx = DOT8(vn, hin, sbx);
                    float r = rcpf_(1.f + ex2(sr));
                    float z = rcpf_(1.f + ex2(sz));
                    float ut = fmaf(r, snh, snx);
                    float n = fmaf(-2.f, rcpf_(ex2(ut) + 1.f), 1.f);
                    hown = fmaf(z, hown - n, n);
                    mycur[j * 64 + u] = hown;
                }
            }
            __syncthreads();
            float* t_ = inp == in0 ? in1 : in0; inp = t_;
            t_ = mycur; mycur = myprv; myprv = t_;
        }
    } else {
        // ---- layer 2: t = (K-2)*S + j; input h1 from hring[1][(K-1)&1]
        v2f wr[8], wz[8], wn[8], vr[8], vz[8], vn[8];
#pragma unroll
        for (int m = 0; m < 8; ++m) {
            wr[m] = ldg2(w_hh + (96 + u) * 16 + 2 * m) * -L2E;
            wz[m] = ldg2(w_hh + (96 + 16 + u) * 16 + 2 * m) * -L2E;
            wn[m] = ldg2(w_hh + (96 + 32 + u) * 16 + 2 * m) * (2.f * L2E);
            vr[m] = ldg2(w_ih12 + (48 + u) * 16 + 2 * m) * -L2E;
            vz[m] = ldg2(w_ih12 + (48 + 16 + u) * 16 + 2 * m) * -L2E;
            vn[m] = ldg2(w_ih12 + (48 + 32 + u) * 16 + 2 * m) * (2.f * L2E);
        }
        const v2f sbr = {-(ldg1(b_ih + 96 + u) + ldg1(b_hh + 96 + u)) * L2E, 0.f};
        const v2f sbz = {-(ldg1(b_ih + 112 + u) + ldg1(b_hh + 112 + u)) * L2E, 0.f};
        const v2f sbn = {ldg1(b_hh + 128 + u) * (2.f * L2E), 0.f};
        const v2f sbx = {ldg1(b_ih + 128 + u) * (2.f * L2E), 0.f};
        float* in0 = &hring[1][0][0][s][0];
        float* in1 = &hring[1][1][0][s][0];
        float* my0 = &hring[2][0][0][s][0];
        float* my1 = &hring[2][1][0][s][0];
        float* inp = in1;
        float* mycur = my0; float* myprv = my1;
        float hown = 0.f;
        for (int K = 0; K < NK; ++K) {
            if (K >= 2) {
#pragma unroll
                for (int j = 0; j < S; ++j) {
                    const float* rin = inp + j * 64;
                    const float* rown = (j == 0) ? (myprv + (S - 1) * 64)
                                                 : (mycur + (j - 1) * 64);
                    v2f hin[8], hp[8];
                    RDH(hin, rin);
                    RDH(hp, rown);
                    float sr = DOT16(wr, hp, vr, hin, sbr);
                    float sz = DOT16(wz, hp, vz, hin, sbz);
                    float snh = DOT8(wn, hp, sbn);
                    float snx = DOT8(vn, hin, sbx);
                    float r = rcpf_(1.f + ex2(sr));
                    float z = rcpf_(1.f + ex2(sz));
                    float ut = fmaf(r, snh, snx);
                    float n = fmaf(-2.f, rcpf_(ex2(ut) + 1.f), 1.f);
                    hown = fmaf(z, hown - n, n);
                    mycur[j * 64 + u] = hown;
                }
            }
            __syncthreads();
            float* t_ = inp == in0 ? in1 : in0; inp = t_;
            t_ = mycur; mycur = myprv; myprv = t_;
        }
        // ---- head on h2(1023): hown holds it; same-wave LDS staging
        h2f[s][u] = hown;
        if (u < 5) {
            float acc = fc_b[u];
#pragma unroll
            for (int j = 0; j < 16; ++j)
                acc = fmaf(fc_w[u * 16 + j], h2f[s][j], acc);
            out[seq * 5 + u] = acc;
        }
    }
}

extern "C" void kernel_launch(void* const* d_in, const int* in_sizes, int n_in,
                              void* d_out, int out_size, void* d_ws, size_t ws_size,
                              hipStream_t stream) {
    const float* x      = (const float*)d_in[0];
    const float* w_ih0  = (const float*)d_in[1];
    const float* w_ih12 = (const float*)d_in[2];
    const float* w_hh   = (const float*)d_in[3];
    const float* b_ih   = (const float*)d_in[4];
    const float* b_hh   = (const float*)d_in[5];
    const float* fc_w   = (const float*)d_in[6];
    const float* fc_b   = (const float*)d_in[7];
    float* out = (float*)d_out;

    // 1024 blocks x 192 threads (3 waves: L0,L1,L2; 4 seqs/block)
    gru3_sk8b<<<1024, 192, 0, stream>>>(
        x, w_ih0, w_ih12, w_hh, b_ih, b_hh, fc_w, fc_b, out);
}

// Round 23
// 488.453 us; speedup vs baseline: 1.3932x; 1.0635x over previous
//
#include <hip/hip_runtime.h>
#include <stdint.h>

#define TSTEPS 1024
#define S 8          // timesteps per super-iter (layer skew)
#define NK 130       // 1024/S + 2 pipeline-drain super-iters
#define L2E 1.4426950408889634f
#define XPITCH 1028  // padded x row (dwords): bank-spread rows, 16B-aligned

typedef float v2f __attribute__((ext_vector_type(2)));
typedef float v4f __attribute__((ext_vector_type(4)));

__device__ __forceinline__ float rcpf_(float v) { return __builtin_amdgcn_rcpf(v); }
__device__ __forceinline__ float ex2(float v) { return __builtin_amdgcn_exp2f(v); }
#define PKFMA(a, b, c) __builtin_elementwise_fma((a), (b), (c))

// Opaque loads: value is asm-produced -> cannot be rematerialized as a load.
__device__ __forceinline__ v2f ldg2(const float* p) {
    v2f r; uint64_t a = (uint64_t)p;
    asm volatile("global_load_dwordx2 %0, %1, off\n\ts_waitcnt vmcnt(0)"
                 : "=v"(r) : "v"(a));
    return r;
}
__device__ __forceinline__ float ldg1(const float* p) {
    float r; uint64_t a = (uint64_t)p;
    asm volatile("global_load_dword %0, %1, off\n\ts_waitcnt vmcnt(0)"
                 : "=v"(r) : "v"(a));
    return r;
}

// read 16 consecutive LDS floats (one h vector) into 8 v2f (4x ds_read_b128)
#define RDH(dst, p)                                                        \
    do {                                                                   \
        v4f a0 = *(const v4f*)(p);                                         \
        v4f a1 = *(const v4f*)((p) + 4);                                   \
        v4f a2 = *(const v4f*)((p) + 8);                                   \
        v4f a3 = *(const v4f*)((p) + 12);                                  \
        dst[0] = __builtin_shufflevector(a0, a0, 0, 1);                    \
        dst[1] = __builtin_shufflevector(a0, a0, 2, 3);                    \
        dst[2] = __builtin_shufflevector(a1, a1, 0, 1);                    \
        dst[3] = __builtin_shufflevector(a1, a1, 2, 3);                    \
        dst[4] = __builtin_shufflevector(a2, a2, 0, 1);                    \
        dst[5] = __builtin_shufflevector(a2, a2, 2, 3);                    \
        dst[6] = __builtin_shufflevector(a3, a3, 0, 1);                    \
        dst[7] = __builtin_shufflevector(a3, a3, 2, 3);                    \
    } while (0)

#define DOT8(w, h, seed)                                                   \
    ({                                                                     \
        v2f _a = PKFMA(w[0], h[0], (seed));                                \
        _a = PKFMA(w[1], h[1], _a); _a = PKFMA(w[2], h[2], _a);            \
        _a = PKFMA(w[3], h[3], _a); _a = PKFMA(w[4], h[4], _a);            \
        _a = PKFMA(w[5], h[5], _a); _a = PKFMA(w[6], h[6], _a);            \
        _a = PKFMA(w[7], h[7], _a);                                        \
        _a.x + _a.y;                                                       \
    })
#define DOT16(wa, ha, wb, hb, seed)                                        \
    ({                                                                     \
        v2f _a = PKFMA(wa[0], ha[0], (seed));                              \
        _a = PKFMA(wa[1], ha[1], _a); _a = PKFMA(wa[2], ha[2], _a);        \
        _a = PKFMA(wa[3], ha[3], _a); _a = PKFMA(wa[4], ha[4], _a);        \
        _a = PKFMA(wa[5], ha[5], _a); _a = PKFMA(wa[6], ha[6], _a);        \
        _a = PKFMA(wa[7], ha[7], _a);                                      \
        _a = PKFMA(wb[0], hb[0], _a); _a = PKFMA(wb[1], hb[1], _a);        \
        _a = PKFMA(wb[2], hb[2], _a); _a = PKFMA(wb[3], hb[3], _a);        \
        _a = PKFMA(wb[4], hb[4], _a); _a = PKFMA(wb[5], hb[5], _a);        \
        _a = PKFMA(wb[6], hb[6], _a); _a = PKFMA(wb[7], hb[7], _a);        \
        _a.x + _a.y;                                                       \
    })

// Block = 3 waves (one per layer) x 4 seqs. Layers skewed by S timesteps;
// cross-layer h handoff through double-buffered rings (buf = K&1), barrier
// once per super-iter (130 total at S=8). Own-layer recurrent reads are
// same-wave DS (program-ordered) and never wait on the barrier.
// [Session best: 487.7 us, R20]
__global__ __launch_bounds__(192, 3)
__attribute__((amdgpu_waves_per_eu(3, 3)))
void gru3_sk8(
    const float* __restrict__ x,      // [4096,1024,1]
    const float* __restrict__ w_ih0,  // [48,1]
    const float* __restrict__ w_ih12, // [2,48,16]
    const float* __restrict__ w_hh,   // [3,48,16]
    const float* __restrict__ b_ih,   // [3,48]
    const float* __restrict__ b_hh,   // [3,48]
    const float* __restrict__ fc_w,   // [5,16]
    const float* __restrict__ fc_b,   // [5]
    float* __restrict__ out)          // [4096,5]
{
    __shared__ float xs[4][XPITCH];          // padded x rows
    __shared__ float hring[3][2][S][4][16];  // [layer][buf][slot][seq][unit]
    __shared__ float h2f[4][16];             // head staging

    const int tid = threadIdx.x;
    const int role = tid >> 6;         // wave = layer
    const int lane = tid & 63;
    const int s = lane >> 4;           // seq within block (0..3)
    const int u = lane & 15;           // hidden unit
    const int seq = blockIdx.x * 4 + s;

    // ---- stage x (coalesced float4, padded rows) + zero rings
    {
        const float4* xg = (const float4*)(x + (size_t)blockIdx.x * 4 * TSTEPS);
#pragma unroll
        for (int j = 0; j < 6; ++j) {
            int idx = tid + 192 * j;
            if (idx < 1024) {
                float4 v = xg[idx];
                *(float4*)&xs[idx >> 8][(idx & 255) * 4] = v;
            }
        }
#pragma unroll
        for (int j = 0; j < 16; ++j)
            ((float*)hring)[tid + 192 * j] = 0.f;
    }
    __syncthreads();

    if (role == 0) {
        // ---- layer 0: t = K*S + j
        v2f wr[8], wz[8], wn[8];
#pragma unroll
        for (int m = 0; m < 8; ++m) {
            wr[m] = ldg2(w_hh + (u) * 16 + 2 * m) * -L2E;
            wz[m] = ldg2(w_hh + (16 + u) * 16 + 2 * m) * -L2E;
            wn[m] = ldg2(w_hh + (32 + u) * 16 + 2 * m) * (2.f * L2E);
        }
        const float wxr = ldg1(w_ih0 + u) * -L2E;
        const float wxz = ldg1(w_ih0 + 16 + u) * -L2E;
        const float wxn = ldg1(w_ih0 + 32 + u) * (2.f * L2E);
        const v2f sbr = {-(ldg1(b_ih + u) + ldg1(b_hh + u)) * L2E, 0.f};
        const v2f sbz = {-(ldg1(b_ih + 16 + u) + ldg1(b_hh + 16 + u)) * L2E, 0.f};
        const v2f sbn = {ldg1(b_hh + 32 + u) * (2.f * L2E), 0.f};
        const float bnx = ldg1(b_ih + 32 + u) * (2.f * L2E);
        float* cur = &hring[0][0][0][s][0];  // buf K&1 (slot stride 64 floats)
        float* prv = &hring[0][1][0][s][0];
        float hown = 0.f;
        for (int K = 0; K < NK; ++K) {
            if (K < 128) {
                v4f xq0 = *(const v4f*)&xs[s][K * S];
                v4f xq1 = *(const v4f*)&xs[s][K * S + 4];
#pragma unroll
                for (int j = 0; j < S; ++j) {
                    const float* rb = (j == 0) ? (prv + (S - 1) * 64)
                                               : (cur + (j - 1) * 64);
                    v2f hp[8];
                    RDH(hp, rb);
                    float xt = (j < 4) ? xq0[j] : xq1[j - 4];
                    float sr = fmaf(wxr, xt, DOT8(wr, hp, sbr));
                    float sz = fmaf(wxz, xt, DOT8(wz, hp, sbz));
                    float snh = DOT8(wn, hp, sbn);
                    float r = rcpf_(1.f + ex2(sr));
                    float z = rcpf_(1.f + ex2(sz));
                    float ut = fmaf(r, snh, fmaf(wxn, xt, bnx));
                    float n = fmaf(-2.f, rcpf_(ex2(ut) + 1.f), 1.f);
                    hown = fmaf(z, hown - n, n);
                    cur[j * 64 + u] = hown;
                }
            }
            __syncthreads();
            float* t_ = cur; cur = prv; prv = t_;
        }
    } else if (role == 1) {
        // ---- layer 1: t = (K-1)*S + j; input h0 from hring[0][(K-1)&1]
        v2f wr[8], wz[8], wn[8], vr[8], vz[8], vn[8];
#pragma unroll
        for (int m = 0; m < 8; ++m) {
            wr[m] = ldg2(w_hh + (48 + u) * 16 + 2 * m) * -L2E;
            wz[m] = ldg2(w_hh + (48 + 16 + u) * 16 + 2 * m) * -L2E;
            wn[m] = ldg2(w_hh + (48 + 32 + u) * 16 + 2 * m) * (2.f * L2E);
            vr[m] = ldg2(w_ih12 + (u) * 16 + 2 * m) * -L2E;
            vz[m] = ldg2(w_ih12 + (16 + u) * 16 + 2 * m) * -L2E;
            vn[m] = ldg2(w_ih12 + (32 + u) * 16 + 2 * m) * (2.f * L2E);
        }
        const v2f sbr = {-(ldg1(b_ih + 48 + u) + ldg1(b_hh + 48 + u)) * L2E, 0.f};
        const v2f sbz = {-(ldg1(b_ih + 64 + u) + ldg1(b_hh + 64 + u)) * L2E, 0.f};
        const v2f sbn = {ldg1(b_hh + 80 + u) * (2.f * L2E), 0.f};
        const v2f sbx = {ldg1(b_ih + 80 + u) * (2.f * L2E), 0.f};
        float* in0 = &hring[0][0][0][s][0];
        float* in1 = &hring[0][1][0][s][0];
        float* my0 = &hring[1][0][0][s][0];
        float* my1 = &hring[1][1][0][s][0];
        float* inp = in1;  // at K: in[(K-1)&1]; K=0 -> [1] (unused), swap->K=1:[0]
        float* mycur = my0; float* myprv = my1;
        float hown = 0.f;
        for (int K = 0; K < NK; ++K) {
            if (K >= 1 && K < 129) {
#pragma unroll
                for (int j = 0; j < S; ++j) {
                    const float* rin = inp + j * 64;
                    const float* rown = (j == 0) ? (myprv + (S - 1) * 64)
                                                 : (mycur + (j - 1) * 64);
                    v2f hin[8], hp[8];
                    RDH(hin, rin);
                    RDH(hp, rown);
                    float sr = DOT16(wr, hp, vr, hin, sbr);
                    float sz = DOT16(wz, hp, vz, hin, sbz);
                    float snh = DOT8(wn, hp, sbn);
                    float snx = DOT8(vn, hin, sbx);
                    float r = rcpf_(1.f + ex2(sr));
                    float z = rcpf_(1.f + ex2(sz));
                    float ut = fmaf(r, snh, snx);
                    float n = fmaf(-2.f, rcpf_(ex2(ut) + 1.f), 1.f);
                    hown = fmaf(z, hown - n, n);
                    mycur[j * 64 + u] = hown;
                }
            }
            __syncthreads();
            float* t_ = inp == in0 ? in1 : in0; inp = t_;
            t_ = mycur; mycur = myprv; myprv = t_;
        }
    } else {
        // ---- layer 2: t = (K-2)*S + j; input h1 from hring[1][(K-1)&1]
        v2f wr[8], wz[8], wn[8], vr[8], vz[8], vn[8];
#pragma unroll
        for (int m = 0; m < 8; ++m) {
            wr[m] = ldg2(w_hh + (96 + u) * 16 + 2 * m) * -L2E;
            wz[m] = ldg2(w_hh + (96 + 16 + u) * 16 + 2 * m) * -L2E;
            wn[m] = ldg2(w_hh + (96 + 32 + u) * 16 + 2 * m) * (2.f * L2E);
            vr[m] = ldg2(w_ih12 + (48 + u) * 16 + 2 * m) * -L2E;
            vz[m] = ldg2(w_ih12 + (48 + 16 + u) * 16 + 2 * m) * -L2E;
            vn[m] = ldg2(w_ih12 + (48 + 32 + u) * 16 + 2 * m) * (2.f * L2E);
        }
        const v2f sbr = {-(ldg1(b_ih + 96 + u) + ldg1(b_hh + 96 + u)) * L2E, 0.f};
        const v2f sbz = {-(ldg1(b_ih + 112 + u) + ldg1(b_hh + 112 + u)) * L2E, 0.f};
        const v2f sbn = {ldg1(b_hh + 128 + u) * (2.f * L2E), 0.f};
        const v2f sbx = {ldg1(b_ih + 128 + u) * (2.f * L2E), 0.f};
        float* in0 = &hring[1][0][0][s][0];
        float* in1 = &hring[1][1][0][s][0];
        float* my0 = &hring[2][0][0][s][0];
        float* my1 = &hring[2][1][0][s][0];
        float* inp = in1;
        float* mycur = my0; float* myprv = my1;
        float hown = 0.f;
        for (int K = 0; K < NK; ++K) {
            if (K >= 2) {
#pragma unroll
                for (int j = 0; j < S; ++j) {
                    const float* rin = inp + j * 64;
                    const float* rown = (j == 0) ? (myprv + (S - 1) * 64)
                                                 : (mycur + (j - 1) * 64);
                    v2f hin[8], hp[8];
                    RDH(hin, rin);
                    RDH(hp, rown);
                    float sr = DOT16(wr, hp, vr, hin, sbr);
                    float sz = DOT16(wz, hp, vz, hin, sbz);
                    float snh = DOT8(wn, hp, sbn);
                    float snx = DOT8(vn, hin, sbx);
                    float r = rcpf_(1.f + ex2(sr));
                    float z = rcpf_(1.f + ex2(sz));
                    float ut = fmaf(r, snh, snx);
                    float n = fmaf(-2.f, rcpf_(ex2(ut) + 1.f), 1.f);
                    hown = fmaf(z, hown - n, n);
                    mycur[j * 64 + u] = hown;
                }
            }
            __syncthreads();
            float* t_ = inp == in0 ? in1 : in0; inp = t_;
            t_ = mycur; mycur = myprv; myprv = t_;
        }
        // ---- head on h2(1023): hown holds it; same-wave LDS staging
        h2f[s][u] = hown;
        if (u < 5) {
            float acc = fc_b[u];
#pragma unroll
            for (int j = 0; j < 16; ++j)
                acc = fmaf(fc_w[u * 16 + j], h2f[s][j], acc);
            out[seq * 5 + u] = acc;
        }
    }
}

extern "C" void kernel_launch(void* const* d_in, const int* in_sizes, int n_in,
                              void* d_out, int out_size, void* d_ws, size_t ws_size,
                              hipStream_t stream) {
    const float* x      = (const float*)d_in[0];
    const float* w_ih0  = (const float*)d_in[1];
    const float* w_ih12 = (const float*)d_in[2];
    const float* w_hh   = (const float*)d_in[3];
    const float* b_ih   = (const float*)d_in[4];
    const float* b_hh   = (const float*)d_in[5];
    const float* fc_w   = (const float*)d_in[6];
    const float* fc_b   = (const float*)d_in[7];
    float* out = (float*)d_out;

    // 1024 blocks x 192 threads (3 waves: L0,L1,L2; 4 seqs/block)
    // -> 3072 waves -> 3 waves/SIMD, barrier domain = 3 waves.
    gru3_sk8<<<1024, 192, 0, stream>>>(
        x, w_ih0, w_ih12, w_hh, b_ih, b_hh, fc_w, fc_b, out);
}